// Round 17
// baseline (228.053 us; speedup 1.0000x reference)
//
#include <hip/hip_runtime.h>

typedef unsigned short u16;
typedef unsigned int u32;
typedef __attribute__((ext_vector_type(8))) short s16x8;
typedef __attribute__((ext_vector_type(4))) float f32x4;
typedef __attribute__((ext_vector_type(4))) int i32x4;

#define PS 1572864  // 2048*768 partial stride (elems)

// ---------- bf16 helpers (bit-level, RNE) ----------
static __device__ __forceinline__ float bf2f(u16 u) {
    return __uint_as_float(((u32)u) << 16);
}
static __device__ __forceinline__ u16 f2bf(float f) {
    u32 x = __float_as_uint(f);
    return (u16)((x + 0x7fffu + ((x >> 16) & 1u)) >> 16);
}
static __device__ __forceinline__ i32x4 pack8(float4 a, float4 b) {
    u32 p0 = (u32)f2bf(a.x) | ((u32)f2bf(a.y) << 16);
    u32 p1 = (u32)f2bf(a.z) | ((u32)f2bf(a.w) << 16);
    u32 p2 = (u32)f2bf(b.x) | ((u32)f2bf(b.y) << 16);
    u32 p3 = (u32)f2bf(b.z) | ((u32)f2bf(b.w) << 16);
    return (i32x4){(int)p0, (int)p1, (int)p2, (int)p3};
}
static __device__ __forceinline__ float wave_sum(float v) {
#pragma unroll
    for (int off = 32; off > 0; off >>= 1) v += __shfl_xor(v, off);
    return v;
}
// async global->LDS, 16B per lane; dest is wave-uniform base (+lane*16 by HW)
static __device__ __forceinline__ void gload16(const void* g, void* l) {
    __builtin_amdgcn_global_load_lds((const __attribute__((address_space(1))) void*)g,
                                     (__attribute__((address_space(3))) void*)l, 16, 0, 0);
}
// f32 LDS B-tile fragment read -> bf16 frag (tile [64 col][32 k] f32, 128B row)
static __device__ __forceinline__ s16x8 bfrag_f32(const char* base, int cb, int lane) {
    int g = (lane >> 4) * 2;
    const char* bb = base + cb * 128;
    float4 lo = *(const float4*)(bb + ((g ^ (cb & 7)) * 16));
    float4 hi = *(const float4*)(bb + (((g + 1) ^ (cb & 7)) * 16));
    i32x4 p = pack8(lo, hi);
    return *(s16x8*)&p;
}

// ---------- adaLN GEMM + CA K/V prep (weights consumed fp32 by GEMMs now) ----------
// blocks [0,1728): mod = silu(c) @ ada_w.T + ada_b (wave per output).
// blocks [1728,2112): CA K/V prep (cond-RMS -> K/V proj -> K head-RMS).
__global__ __launch_bounds__(256) void ada_kv(const float* __restrict__ c,
                                              const float* __restrict__ adaw,
                                              const float* __restrict__ adab,
                                              float* __restrict__ mod,
                                              const float* __restrict__ cond,
                                              const float* __restrict__ cnw,
                                              const float* __restrict__ cakw,
                                              const float* __restrict__ cavw,
                                              const float* __restrict__ caknw,
                                              float* __restrict__ kca,
                                              float* __restrict__ vca) {
    const int bid = blockIdx.x;
    const int tid = threadIdx.x;
    if (bid < 1728) {
        int wid = bid * 4 + (tid >> 6);
        int lane = tid & 63;
        float sum = 0.f;
#pragma unroll
        for (int i = 0; i < 12; ++i) {
            float cv = c[i * 64 + lane];
            cv = cv / (1.f + __expf(-cv));
            sum += cv * adaw[(size_t)wid * 768 + i * 64 + lane];
        }
        sum = wave_sum(sum);
        if (lane == 0) mod[wid] = sum + adab[wid];
    } else {
        int b = bid - 1728;
        int which = b / 192;
        int rem = b % 192;
        int rrow = rem / 12, h = rem % 12;
        int w = tid >> 6, lane = tid & 63;
        __shared__ float kvsh[64];
        float cv[12];
        float ss = 0.f;
#pragma unroll
        for (int i = 0; i < 12; ++i) {
            cv[i] = cond[(size_t)rrow * 768 + i * 64 + lane];
            ss += cv[i] * cv[i];
        }
        ss = wave_sum(ss);
        float rn = rsqrtf(ss * (1.f / 768.f) + 1e-6f);
#pragma unroll
        for (int i = 0; i < 12; ++i) cv[i] = cv[i] * rn * cnw[i * 64 + lane];
        const float* Wm = which ? cavw : cakw;
#pragma unroll
        for (int j = 0; j < 16; ++j) {
            int ocol = h * 64 + w * 16 + j;
            float d = 0.f;
#pragma unroll
            for (int i = 0; i < 12; ++i)
                d += cv[i] * Wm[(size_t)ocol * 768 + i * 64 + lane];
            d = wave_sum(d);
            if (lane == 0) kvsh[w * 16 + j] = d;
        }
        __syncthreads();
        if (tid < 64) {
            float v = kvsh[lane];
            if (which == 0) {
                float sk = wave_sum(v * v);
                v = v * rsqrtf(sk * (1.f / 64.f) + 1e-6f) * caknw[lane];
                kca[(size_t)rrow * 768 + h * 64 + lane] = v;
            } else {
                vca[(size_t)rrow * 768 + h * 64 + lane] = v;
            }
        }
    }
}

// ---------- fused RMSNorm + modulate, writes bf16 ----------
__global__ __launch_bounds__(256) void rms_mod(const float* __restrict__ x,
                                               const float* __restrict__ w,
                                               const float* __restrict__ mod, int chunk,
                                               u16* __restrict__ out) {
    const int row = blockIdx.x;
    const int tid = threadIdx.x;
    const float* xr = x + (size_t)row * 768;
    float v0 = xr[tid], v1 = xr[256 + tid], v2 = xr[512 + tid];
    float ss = wave_sum(v0 * v0 + v1 * v1 + v2 * v2);
    __shared__ float red[4];
    if ((tid & 63) == 0) red[tid >> 6] = ss;
    __syncthreads();
    float rn = rsqrtf((red[0] + red[1] + red[2] + red[3]) * (1.f / 768.f) + 1e-6f);
    const float* sh = mod + chunk * 768;
    const float* sc = sh + 768;
    u16* orow = out + (size_t)row * 768;
    orow[tid]       = f2bf(v0 * rn * w[tid]       * (1.f + sc[tid])       + sh[tid]);
    orow[256 + tid] = f2bf(v1 * rn * w[256 + tid] * (1.f + sc[256 + tid]) + sh[256 + tid]);
    orow[512 + tid] = f2bf(v2 * rn * w[512 + tid] * (1.f + sc[512 + tid]) + sh[512 + tid]);
}

// ---------- qkv GEMM (B fp32 direct) + QK RMSNorm+RoPE + V-transpose epilogue ----------
__global__ __launch_bounds__(256) void gemm_qkv(const u16* __restrict__ A,
                                                const float* __restrict__ Wf,
                                                u16* __restrict__ qkvb,
                                                u16* __restrict__ vT,
                                                const float* __restrict__ qnw,
                                                const float* __restrict__ knw,
                                                const float* __restrict__ cosT,
                                                const float* __restrict__ sinT,
                                                int C, int R, int nxc) {
    constexpr int K = 768, N = 2304;
    __shared__ __align__(16) char smem[33792];  // stage 32768 | epilogue T 33792 (aliased)
    u16 (*As)[128 * 32] = (u16(*)[128 * 32])smem;
    float (*Bs)[64 * 32] = (float(*)[64 * 32])(smem + 16384);
    const int tid = threadIdx.x;
    const int lane = tid & 63;
    const int w = tid >> 6;
    const int wr = w >> 1, wc = w & 1;
    const int sub = blockIdx.x;
    const int xcd = sub & 7, idx = sub >> 3;
    const int cx = xcd % nxc, cy = xcd / nxc;
    const int col0 = (cx * C + idx % C) << 6;
    const int row0 = (cy * R + idx / C) << 7;

    const int r0u = tid >> 2, s0u = (tid & 3) ^ (r0u & 3);
    const int r1u = (tid + 256) >> 2, s1u = (tid & 3) ^ (r1u & 3);
    const u16* a0 = A + (size_t)(row0 + r0u) * K + s0u * 8;
    const u16* a1 = A + (size_t)(row0 + r1u) * K + s1u * 8;
    const int b0r = tid >> 3, b0s = (tid & 7) ^ (b0r & 7);
    const int b1r = (tid + 256) >> 3, b1s = (tid & 7) ^ (b1r & 7);
    const float* b0 = Wf + (size_t)(col0 + b0r) * K + b0s * 4;
    const float* b1 = Wf + (size_t)(col0 + b1r) * K + b1s * 4;

    f32x4 acc[4][2];
#pragma unroll
    for (int m = 0; m < 4; ++m)
#pragma unroll
        for (int n = 0; n < 2; ++n) acc[m][n] = (f32x4){0.f, 0.f, 0.f, 0.f};

    const int nt = K >> 5;
    int cur = 0;
#define QKV_STAGE(buf, k0)                                  \
    {                                                       \
        char* ad = (char*)As[buf] + w * 1024;               \
        char* bd = (char*)Bs[buf] + w * 1024;               \
        gload16(a0 + (k0), ad);                             \
        gload16(a1 + (k0), ad + 4096);                      \
        gload16(b0 + (k0), bd);                             \
        gload16(b1 + (k0), bd + 4096);                      \
    }
    QKV_STAGE(0, 0)
    for (int t = 0; t < nt; ++t) {
        __syncthreads();
        if (t + 1 < nt) QKV_STAGE(cur ^ 1, (t + 1) << 5)
        s16x8 af[4], bfv[2];
#pragma unroll
        for (int m = 0; m < 4; ++m) {
            int ra = wr * 64 + m * 16 + (lane & 15);
            int u = (lane >> 4) ^ (ra & 3);
            af[m] = *(const s16x8*)((const char*)As[cur] + ra * 64 + u * 16);
        }
#pragma unroll
        for (int n = 0; n < 2; ++n) {
            int cb = wc * 32 + n * 16 + (lane & 15);
            bfv[n] = bfrag_f32((const char*)Bs[cur], cb, lane);
        }
#pragma unroll
        for (int m = 0; m < 4; ++m)
#pragma unroll
            for (int n = 0; n < 2; ++n)
                acc[m][n] = __builtin_amdgcn_mfma_f32_16x16x32_bf16(af[m], bfv[n], acc[m][n], 0, 0, 0);
        cur ^= 1;
    }
#undef QKV_STAGE
    __syncthreads();  // staging buffers free; reuse smem for epilogue tile

    const int region = col0 / 768;           // 0=q 1=k 2=v
    const int h = (col0 % 768) >> 6;
    if (region < 2) {
        float (*T)[66] = (float(*)[66])smem;
#pragma unroll
        for (int m = 0; m < 4; ++m)
#pragma unroll
            for (int n = 0; n < 2; ++n)
#pragma unroll
                for (int i = 0; i < 4; ++i)
                    T[wr * 64 + m * 16 + (lane >> 4) * 4 + i]
                     [wc * 32 + n * 16 + (lane & 15)] = acc[m][n][i];
        __syncthreads();
        const float* wv = region ? knw : qnw;
        const int rl = tid >> 1, half = (tid & 1) * 32;
        float ss = 0.f;
#pragma unroll
        for (int d = 0; d < 32; ++d) {
            float v = T[rl][half + d];
            ss += v * v;
        }
        ss += __shfl_xor(ss, 1);
        float rn = rsqrtf(ss * (1.f / 64.f) + 1e-6f);
        const int ng = row0 + rl;
        u16* orow = qkvb + (size_t)ng * N + col0;
        const float* cr = cosT + ng * 64;
        const float* sr = sinT + ng * 64;
#pragma unroll
        for (int d = 0; d < 32; ++d) {
            int dd = half + d;
            float vn = T[rl][dd] * rn * wv[dd];
            float pt = T[rl][dd ^ 32] * rn * wv[dd ^ 32];
            float rot = (dd < 32) ? -pt : pt;
            orow[dd] = f2bf(vn * cr[dd] + rot * sr[dd]);
        }
    } else {
        u16 (*Tb)[66] = (u16(*)[66])smem;
#pragma unroll
        for (int m = 0; m < 4; ++m)
#pragma unroll
            for (int n = 0; n < 2; ++n)
#pragma unroll
                for (int i = 0; i < 4; ++i) {
                    int rl = wr * 64 + m * 16 + (lane >> 4) * 4 + i;
                    int dd = wc * 32 + n * 16 + (lane & 15);
                    u16 b = f2bf(acc[m][n][i]);
                    qkvb[(size_t)(row0 + rl) * N + col0 + dd] = b;
                    Tb[rl][dd] = b;
                }
        __syncthreads();
        u16* dst = vT + (size_t)h * 131072 + (size_t)lane * 2048 + row0 + w * 32;
#pragma unroll
        for (int g = 0; g < 4; ++g) {
            s16x8 o;
#pragma unroll
            for (int e = 0; e < 8; ++e) o[e] = (short)Tb[w * 32 + g * 8 + e][lane];
            *(s16x8*)(dst + g * 8) = o;
        }
    }
}

// ---------- split-K=4 GEMM (B fp32 direct): BN=64; writes bf16 partial z ----------
__global__ __launch_bounds__(256) void gemm_sk4(const u16* __restrict__ A,
                                                const float* __restrict__ Wf,
                                                int M, int N, int K,
                                                u16* __restrict__ pz,
                                                int C, int R, int nxc,
                                                int nsub, int kslice) {
    __shared__ __align__(16) u16 As[2][128 * 32];
    __shared__ __align__(16) float Bs[2][64 * 32];
    const int tid = threadIdx.x;
    const int lane = tid & 63;
    const int w = tid >> 6;
    const int wr = w >> 1, wc = w & 1;
    const int sub = blockIdx.x % nsub;
    const int z = blockIdx.x / nsub;
    const int xcd = sub & 7, idx = sub >> 3;
    const int cx = xcd % nxc, cy = xcd / nxc;
    const int col0 = (cx * C + idx % C) << 6;
    const int row0 = (cy * R + idx / C) << 7;
    const int kbase = z * kslice;

    const int r0u = tid >> 2, s0u = (tid & 3) ^ (r0u & 3);
    const int r1u = (tid + 256) >> 2, s1u = (tid & 3) ^ (r1u & 3);
    const u16* a0 = A + (size_t)(row0 + r0u) * K + kbase + s0u * 8;
    const u16* a1 = A + (size_t)(row0 + r1u) * K + kbase + s1u * 8;
    const int b0r = tid >> 3, b0s = (tid & 7) ^ (b0r & 7);
    const int b1r = (tid + 256) >> 3, b1s = (tid & 7) ^ (b1r & 7);
    const float* b0 = Wf + (size_t)(col0 + b0r) * K + kbase + b0s * 4;
    const float* b1 = Wf + (size_t)(col0 + b1r) * K + kbase + b1s * 4;

    f32x4 acc[4][2];
#pragma unroll
    for (int m = 0; m < 4; ++m)
#pragma unroll
        for (int n = 0; n < 2; ++n) acc[m][n] = (f32x4){0.f, 0.f, 0.f, 0.f};

    const int nt = kslice >> 5;
    int cur = 0;
#define SK_STAGE(buf, k0)                                   \
    {                                                       \
        char* ad = (char*)As[buf] + w * 1024;               \
        char* bd = (char*)Bs[buf] + w * 1024;               \
        gload16(a0 + (k0), ad);                             \
        gload16(a1 + (k0), ad + 4096);                      \
        gload16(b0 + (k0), bd);                             \
        gload16(b1 + (k0), bd + 4096);                      \
    }
    SK_STAGE(0, 0)
    for (int t = 0; t < nt; ++t) {
        __syncthreads();
        if (t + 1 < nt) SK_STAGE(cur ^ 1, (t + 1) << 5)
        s16x8 af[4], bfv[2];
#pragma unroll
        for (int m = 0; m < 4; ++m) {
            int ra = wr * 64 + m * 16 + (lane & 15);
            int u = (lane >> 4) ^ (ra & 3);
            af[m] = *(const s16x8*)((const char*)As[cur] + ra * 64 + u * 16);
        }
#pragma unroll
        for (int n = 0; n < 2; ++n) {
            int cb = wc * 32 + n * 16 + (lane & 15);
            bfv[n] = bfrag_f32((const char*)Bs[cur], cb, lane);
        }
#pragma unroll
        for (int m = 0; m < 4; ++m)
#pragma unroll
            for (int n = 0; n < 2; ++n)
                acc[m][n] = __builtin_amdgcn_mfma_f32_16x16x32_bf16(af[m], bfv[n], acc[m][n], 0, 0, 0);
        cur ^= 1;
    }
#undef SK_STAGE
    u16* po = pz + (size_t)z * PS;
#pragma unroll
    for (int m = 0; m < 4; ++m)
#pragma unroll
        for (int n = 0; n < 2; ++n)
#pragma unroll
            for (int i = 0; i < 4; ++i) {
                int r = row0 + wr * 64 + m * 16 + (lane >> 4) * 4 + i;
                int cc = col0 + wc * 32 + n * 16 + (lane & 15);
                po[(size_t)r * N + cc] = f2bf(acc[m][n][i]);
            }
}

// ---------- combine 4 split-K partials (elementwise) ----------
template <int MODE>
__global__ __launch_bounds__(256) void comb4(const u16* __restrict__ pz,
                                             const float* __restrict__ resid,
                                             const float* __restrict__ gate,
                                             const float* __restrict__ bias,
                                             float* __restrict__ outf) {
    int base = (blockIdx.x * 256 + threadIdx.x) * 8;
    int col = base % 768;
    s16x8 p0 = *(const s16x8*)(pz + base);
    s16x8 p1 = *(const s16x8*)(pz + PS + base);
    s16x8 p2 = *(const s16x8*)(pz + 2 * PS + base);
    s16x8 p3 = *(const s16x8*)(pz + 3 * PS + base);
    float o[8];
#pragma unroll
    for (int e = 0; e < 8; ++e) {
        float s = (bf2f((u16)p0[e]) + bf2f((u16)p1[e])) +
                  (bf2f((u16)p2[e]) + bf2f((u16)p3[e]));
        if constexpr (MODE == 0) {
            o[e] = s;
        } else {
            float bb = bias ? bias[col + e] : 0.f;
            o[e] = resid[base + e] + gate[col + e] * (s + bb);
        }
    }
    *(float4*)(outf + base) = (float4){o[0], o[1], o[2], o[3]};
    *(float4*)(outf + base + 4) = (float4){o[4], o[5], o[6], o[7]};
}

// ---------- fused: combine 4 partials + residual + RMSNorm + modulate ----------
__global__ __launch_bounds__(256) void comb_rms(const u16* __restrict__ pz,
                                                const float* __restrict__ resid,
                                                const float* __restrict__ gate,
                                                const float* __restrict__ bias,
                                                const float* __restrict__ mod, int chunk,
                                                const float* __restrict__ w,
                                                float* __restrict__ outf,
                                                u16* __restrict__ outb) {
    const int row = blockIdx.x;
    const int tid = threadIdx.x;
    float val[3];
    float ss = 0.f;
#pragma unroll
    for (int j = 0; j < 3; ++j) {
        int col = tid + j * 256;
        size_t ix = (size_t)row * 768 + col;
        float s = (bf2f(pz[ix]) + bf2f(pz[PS + ix])) +
                  (bf2f(pz[2 * PS + ix]) + bf2f(pz[3 * PS + ix]));
        float bb = bias ? bias[col] : 0.f;
        float v = resid[ix] + gate[col] * (s + bb);
        val[j] = v;
        ss += v * v;
        outf[ix] = v;
    }
    ss = wave_sum(ss);
    __shared__ float red[4];
    if ((tid & 63) == 0) red[tid >> 6] = ss;
    __syncthreads();
    float rn = rsqrtf((red[0] + red[1] + red[2] + red[3]) * (1.f / 768.f) + 1e-6f);
    const float* sh = mod + chunk * 768;
    const float* sc = sh + 768;
#pragma unroll
    for (int j = 0; j < 3; ++j) {
        int col = tid + j * 256;
        size_t ix = (size_t)row * 768 + col;
        outb[ix] = f2bf(val[j] * rn * w[col] * (1.f + sc[col]) + sh[col]);
    }
}

// ---------- fused CA: combine 4 q partials + RMS + RoPE + attention ----------
__global__ __launch_bounds__(256) void ca_fused(const u16* __restrict__ pz,
                                                const float* __restrict__ qnw,
                                                const float* __restrict__ cosT,
                                                const float* __restrict__ sinT,
                                                const float* __restrict__ kca,
                                                const float* __restrict__ vca,
                                                u16* __restrict__ obuf) {
    int wid = blockIdx.x * 4 + (threadIdx.x >> 6);
    int lane = threadIdx.x & 63;
    int n = wid / 12, h = wid % 12;
    size_t ix = (size_t)n * 768 + h * 64 + lane;
    float v = (bf2f(pz[ix]) + bf2f(pz[PS + ix])) +
              (bf2f(pz[2 * PS + ix]) + bf2f(pz[3 * PS + ix]));
    float ss = wave_sum(v * v);
    float vn = v * rsqrtf(ss * (1.f / 64.f) + 1e-6f) * qnw[lane];
    float part = __shfl_xor(vn, 32);
    float rot = (lane < 32) ? -part : part;
    float qd = (vn * cosT[n * 64 + lane] + rot * sinT[n * 64 + lane]) * 0.125f;
    float s[16];
#pragma unroll
    for (int j = 0; j < 16; ++j)
        s[j] = wave_sum(qd * kca[(size_t)j * 768 + h * 64 + lane]);
    float mm = s[0];
#pragma unroll
    for (int j = 1; j < 16; ++j) mm = fmaxf(mm, s[j]);
    float l = 0.f;
#pragma unroll
    for (int j = 0; j < 16; ++j) { s[j] = __expf(s[j] - mm); l += s[j]; }
    float od = 0.f;
#pragma unroll
    for (int j = 0; j < 16; ++j) od += s[j] * vca[(size_t)j * 768 + h * 64 + lane];
    obuf[ix] = f2bf(od / l);
}

// ---------- fused MLP-up (W1, W3 fp32 direct): gbuf = bf16(silu(A@W1^T)*(A@W3^T)) ----------
__global__ __launch_bounds__(256) void gemm_w13(const u16* __restrict__ A,
                                                const float* __restrict__ W1,
                                                const float* __restrict__ W3,
                                                int M, int N, int K,
                                                u16* __restrict__ outb,
                                                int C, int R, int nxc) {
    __shared__ __align__(16) u16 As[2][128 * 32];
    __shared__ __align__(16) float B1s[2][64 * 32];
    __shared__ __align__(16) float B3s[2][64 * 32];
    const int tid = threadIdx.x;
    const int lane = tid & 63;
    const int w = tid >> 6;
    const int wr = w >> 1, wc = w & 1;
    const int sub = blockIdx.x;
    const int xcd = sub & 7, idx = sub >> 3;
    const int cx = xcd % nxc, cy = xcd / nxc;
    const int col0 = (cx * C + idx % C) << 6;
    const int row0 = (cy * R + idx / C) << 7;

    const int r0u = tid >> 2, s0u = (tid & 3) ^ (r0u & 3);
    const int r1u = (tid + 256) >> 2, s1u = (tid & 3) ^ (r1u & 3);
    const u16* a0 = A + (size_t)(row0 + r0u) * K + s0u * 8;
    const u16* a1 = A + (size_t)(row0 + r1u) * K + s1u * 8;
    const int b0r = tid >> 3, b0s = (tid & 7) ^ (b0r & 7);
    const int b1r = (tid + 256) >> 3, b1s = (tid & 7) ^ (b1r & 7);
    const float* b10 = W1 + (size_t)(col0 + b0r) * K + b0s * 4;
    const float* b11 = W1 + (size_t)(col0 + b1r) * K + b1s * 4;
    const float* b30 = W3 + (size_t)(col0 + b0r) * K + b0s * 4;
    const float* b31 = W3 + (size_t)(col0 + b1r) * K + b1s * 4;

    f32x4 acc1[4][2], acc3[4][2];
#pragma unroll
    for (int m = 0; m < 4; ++m)
#pragma unroll
        for (int n = 0; n < 2; ++n) {
            acc1[m][n] = (f32x4){0.f, 0.f, 0.f, 0.f};
            acc3[m][n] = (f32x4){0.f, 0.f, 0.f, 0.f};
        }

    const int nt = K >> 5;
    int cur = 0;
#define W13_STAGE(buf, k0)                                  \
    {                                                       \
        char* ad = (char*)As[buf] + w * 1024;               \
        char* bd1 = (char*)B1s[buf] + w * 1024;             \
        char* bd3 = (char*)B3s[buf] + w * 1024;             \
        gload16(a0 + (k0), ad);                             \
        gload16(a1 + (k0), ad + 4096);                      \
        gload16(b10 + (k0), bd1);                           \
        gload16(b11 + (k0), bd1 + 4096);                    \
        gload16(b30 + (k0), bd3);                           \
        gload16(b31 + (k0), bd3 + 4096);                    \
    }
    W13_STAGE(0, 0)
    for (int t = 0; t < nt; ++t) {
        __syncthreads();
        if (t + 1 < nt) W13_STAGE(cur ^ 1, (t + 1) << 5)
        s16x8 af[4], b1v[2], b3v[2];
#pragma unroll
        for (int m = 0; m < 4; ++m) {
            int ra = wr * 64 + m * 16 + (lane & 15);
            int u = (lane >> 4) ^ (ra & 3);
            af[m] = *(const s16x8*)((const char*)As[cur] + ra * 64 + u * 16);
        }
#pragma unroll
        for (int n = 0; n < 2; ++n) {
            int cb = wc * 32 + n * 16 + (lane & 15);
            b1v[n] = bfrag_f32((const char*)B1s[cur], cb, lane);
            b3v[n] = bfrag_f32((const char*)B3s[cur], cb, lane);
        }
#pragma unroll
        for (int m = 0; m < 4; ++m)
#pragma unroll
            for (int n = 0; n < 2; ++n) {
                acc1[m][n] = __builtin_amdgcn_mfma_f32_16x16x32_bf16(af[m], b1v[n], acc1[m][n], 0, 0, 0);
                acc3[m][n] = __builtin_amdgcn_mfma_f32_16x16x32_bf16(af[m], b3v[n], acc3[m][n], 0, 0, 0);
            }
        cur ^= 1;
    }
#undef W13_STAGE
#pragma unroll
    for (int m = 0; m < 4; ++m)
#pragma unroll
        for (int n = 0; n < 2; ++n)
#pragma unroll
            for (int i = 0; i < 4; ++i) {
                int r = row0 + wr * 64 + m * 16 + (lane >> 4) * 4 + i;
                int cc = col0 + wc * 32 + n * 16 + (lane & 15);
                float v1 = acc1[m][n][i];
                float g = v1 / (1.f + __expf(-v1));
                outb[(size_t)r * N + cc] = f2bf(g * acc3[m][n][i]);
            }
}

// ---------- SA flash attention, MFMA bf16, FIXED-MAX softmax + 4-way key split ----------
__global__ __launch_bounds__(256) void sa_attn_mfma(const u16* __restrict__ qkv,
                                                    const u16* __restrict__ vT,
                                                    u16* __restrict__ at,
                                                    float* __restrict__ pl) {
    const int h = blockIdx.y;
    const int r0 = blockIdx.x * 64;
    const int z = blockIdx.z;
    const int tid = threadIdx.x;
    const int lane = tid & 63;
    const int w = tid >> 6;
    __shared__ __align__(16) u16 Ks[2][64 * 64];
    __shared__ __align__(16) u16 Vs[2][64 * 64];
    __shared__ __align__(16) u16 Ps[4][16 * 64];

    s16x8 qf[2];
    {
        const u16* qrow = qkv + (size_t)(r0 + w * 16 + (lane & 15)) * 2304 + h * 64 + ((lane >> 4) * 8);
        qf[0] = *(const s16x8*)qrow;
        qf[1] = *(const s16x8*)(qrow + 32);
    }
    f32x4 oacc[4];
#pragma unroll
    for (int n = 0; n < 4; ++n) oacc[n] = (f32x4){0.f, 0.f, 0.f, 0.f};
    float lp[4] = {0.f, 0.f, 0.f, 0.f};

    const u16* ksrc[2];
    const u16* vsrc[2];
#pragma unroll
    for (int j = 0; j < 2; ++j) {
        int u = (w * 2 + j) * 64 + lane;
        int row = u >> 3, seg = (u & 7) ^ (row & 7);
        ksrc[j] = qkv + (size_t)(z * 512 + row) * 2304 + 768 + h * 64 + seg * 8;
        vsrc[j] = vT + (size_t)h * 131072 + (size_t)row * 2048 + z * 512 + seg * 8;
    }

#define SA_STAGE(buf, t_)                                          \
    {                                                              \
        char* kd = (char*)Ks[buf] + w * 2048;                      \
        char* vd = (char*)Vs[buf] + w * 2048;                      \
        gload16(ksrc[0] + (size_t)(t_) * 147456, kd);              \
        gload16(ksrc[1] + (size_t)(t_) * 147456, kd + 1024);       \
        gload16(vsrc[0] + (t_) * 64, vd);                          \
        gload16(vsrc[1] + (t_) * 64, vd + 1024);                   \
    }

    SA_STAGE(0, 0)
    int cur = 0;
    for (int t = 0; t < 8; ++t) {
        __syncthreads();
        if (t + 1 < 8) SA_STAGE(cur ^ 1, t + 1)

        f32x4 sacc[4];
#pragma unroll
        for (int n = 0; n < 4; ++n) sacc[n] = (f32x4){0.f, 0.f, 0.f, 0.f};
#pragma unroll
        for (int kk = 0; kk < 2; ++kk) {
#pragma unroll
            for (int n = 0; n < 4; ++n) {
                int key = n * 16 + (lane & 15);
                int d = kk * 32 + (lane >> 4) * 8;
                int boff = key * 128 + ((d * 2) ^ ((key & 7) << 4));
                s16x8 kf = *(const s16x8*)((const char*)Ks[cur] + boff);
                sacc[n] = __builtin_amdgcn_mfma_f32_16x16x32_bf16(qf[kk], kf, sacc[n], 0, 0, 0);
            }
        }
        // fixed-max softmax: p = exp(s*0.125 - 8); |s*0.125| <= 8 by Cauchy-Schwarz
#pragma unroll
        for (int n = 0; n < 4; ++n) {
#pragma unroll
            for (int i = 0; i < 4; ++i) {
                float p = __expf(fmaf(sacc[n][i], 0.125f, -8.0f));
                lp[i] += p;
                int row = (lane >> 4) * 4 + i;
                int key = n * 16 + (lane & 15);
                int boff = row * 128 + ((key * 2) ^ ((row & 7) << 4));
                *(u16*)((char*)Ps[w] + boff) = f2bf(p);
            }
        }
#pragma unroll
        for (int kk = 0; kk < 2; ++kk) {
            int koff = kk * 32 + (lane >> 4) * 8;
            int prow = lane & 15;
            int pboff = prow * 128 + ((koff * 2) ^ ((prow & 7) << 4));
            s16x8 pf = *(const s16x8*)((const char*)Ps[w] + pboff);
#pragma unroll
            for (int n = 0; n < 4; ++n) {
                int d = n * 16 + (lane & 15);
                int vboff = d * 128 + ((koff * 2) ^ ((d & 7) << 4));
                s16x8 vf = *(const s16x8*)((const char*)Vs[cur] + vboff);
                oacc[n] = __builtin_amdgcn_mfma_f32_16x16x32_bf16(pf, vf, oacc[n], 0, 0, 0);
            }
        }
        cur ^= 1;
    }
#undef SA_STAGE
#pragma unroll
    for (int off = 1; off < 16; off <<= 1) {
#pragma unroll
        for (int i = 0; i < 4; ++i) lp[i] += __shfl_xor(lp[i], off);
    }
    u16* po = at + (size_t)z * PS;
#pragma unroll
    for (int n = 0; n < 4; ++n) {
#pragma unroll
        for (int i = 0; i < 4; ++i) {
            int r = r0 + w * 16 + (lane >> 4) * 4 + i;
            int d = n * 16 + (lane & 15);
            po[(size_t)r * 768 + h * 64 + d] = f2bf(oacc[n][i]);
        }
    }
    if ((lane & 15) == 0) {
#pragma unroll
        for (int i = 0; i < 4; ++i) {
            int r = r0 + w * 16 + (lane >> 4) * 4 + i;
            pl[z * 24576 + h * 2048 + r] = lp[i];
        }
    }
}

// ---------- combine 4 key-split partials: O = (sum O_z)/(sum l_z) ----------
__global__ __launch_bounds__(256) void sa_combine4(const u16* __restrict__ at,
                                                   const float* __restrict__ pl,
                                                   u16* __restrict__ obuf) {
    int idx = blockIdx.x * 256 + threadIdx.x;
    int base = idx * 8;
    int row = base / 768;
    int col = base % 768;
    int h = col >> 6;
    float l = (pl[h * 2048 + row] + pl[24576 + h * 2048 + row]) +
              (pl[49152 + h * 2048 + row] + pl[73728 + h * 2048 + row]);
    float inv = 1.f / l;
    s16x8 a = *(const s16x8*)(at + base);
    s16x8 b = *(const s16x8*)(at + PS + base);
    s16x8 cc = *(const s16x8*)(at + 2 * PS + base);
    s16x8 d = *(const s16x8*)(at + 3 * PS + base);
    s16x8 o;
#pragma unroll
    for (int e = 0; e < 8; ++e) {
        float s = (bf2f((u16)a[e]) + bf2f((u16)b[e])) +
                  (bf2f((u16)cc[e]) + bf2f((u16)d[e]));
        o[e] = (short)f2bf(s * inv);
    }
    *(s16x8*)(obuf + base) = o;
}

// =======================================================================
extern "C" void kernel_launch(void* const* d_in, const int* in_sizes, int n_in,
                              void* d_out, int out_size, void* d_ws, size_t ws_size,
                              hipStream_t stream) {
    const float* x     = (const float*)d_in[0];
    const float* c     = (const float*)d_in[1];
    const float* cond  = (const float*)d_in[2];
    const float* cosT  = (const float*)d_in[3];
    const float* sinT  = (const float*)d_in[4];
    const float* n1w   = (const float*)d_in[5];
    const float* n2w   = (const float*)d_in[6];
    const float* n3w   = (const float*)d_in[7];
    const float* cnw   = (const float*)d_in[8];
    const float* saqkvw  = (const float*)d_in[9];
    const float* saprojw = (const float*)d_in[10];
    const float* saprojb = (const float*)d_in[11];
    const float* saqnw   = (const float*)d_in[12];
    const float* saknw   = (const float*)d_in[13];
    const float* caqw    = (const float*)d_in[14];
    const float* cakw    = (const float*)d_in[15];
    const float* cavw    = (const float*)d_in[16];
    const float* caprojw = (const float*)d_in[17];
    const float* caprojb = (const float*)d_in[18];
    const float* caqnw   = (const float*)d_in[19];
    const float* caknw   = (const float*)d_in[20];
    const float* w1      = (const float*)d_in[21];
    const float* w2      = (const float*)d_in[22];
    const float* w3      = (const float*)d_in[23];
    const float* adaw    = (const float*)d_in[24];
    const float* adab    = (const float*)d_in[25];
    float* out = (float*)d_out;
    char* ws = (char*)d_ws;

    float* mod  = (float*)ws;                      // 27,648
    u16* hbuf   = (u16*)(ws + 32768);              // 3,145,728
    u16* obuf   = (u16*)(ws + 3178496);            // 3,145,728
    char* R1    = ws + 6324224;                    // shared region
    u16* qkvb   = (u16*)R1;                        //   qkv bf16 [2048][2304]
    u16* vTb    = (u16*)(R1 + 9437184);            //   V^T bf16 [12][64][2048]
    u16* gbuf   = (u16*)R1;                        //   MLP gate bf16 [2048][3072]
    float* kca  = (float*)(ws + 18956288);
    float* vca  = (float*)(ws + 19005440);
    u16* AT     = (u16*)(ws + 40288256);           // attn partials [4][2048][768]
    float* PL4  = (float*)(ws + 52871168);         // attn l [4][12][2048]
    u16* SKP    = (u16*)(ws + 53264384);           // split-K partials [4][2048][768]

    // 1. adaLN + CA K/V prep (weights consumed fp32 directly by GEMMs)
    ada_kv<<<2112, 256, 0, stream>>>(c, adaw, adab, mod,
                                     cond, cnw, cakw, cavw, caknw, kca, vca);

    // ---- self-attention ----
    rms_mod<<<2048, 256, 0, stream>>>(x, n1w, mod, 0, hbuf);
    gemm_qkv<<<576, 256, 0, stream>>>(hbuf, saqkvw, qkvb, vTb,
                                      saqnw, saknw, cosT, sinT, 9, 8, 4);
    sa_attn_mfma<<<dim3(32, 12, 4), 256, 0, stream>>>(qkvb, vTb, AT, PL4);
    sa_combine4<<<768, 256, 0, stream>>>(AT, PL4, obuf);
    gemm_sk4<<<768, 256, 0, stream>>>(obuf, saprojw, 2048, 768, 768,
                                      SKP, 6, 4, 2, 192, 192);
    comb_rms<<<2048, 256, 0, stream>>>(SKP, x, mod + 2 * 768, saprojb,
                                       mod, 3, n2w, out, hbuf);

    // ---- cross-attention ----
    gemm_sk4<<<768, 256, 0, stream>>>(hbuf, caqw, 2048, 768, 768,
                                      SKP, 6, 4, 2, 192, 192);
    ca_fused<<<6144, 256, 0, stream>>>(SKP, caqnw, cosT, sinT, kca, vca, obuf);
    gemm_sk4<<<768, 256, 0, stream>>>(obuf, caprojw, 2048, 768, 768,
                                      SKP, 6, 4, 2, 192, 192);
    comb_rms<<<2048, 256, 0, stream>>>(SKP, out, mod + 5 * 768, caprojb,
                                       mod, 6, n3w, out, hbuf);

    // ---- SwiGLU MLP ----
    gemm_w13<<<768, 256, 0, stream>>>(hbuf, w1, w3,
                                      2048, 3072, 768, gbuf, 12, 8, 4);
    gemm_sk4<<<768, 256, 0, stream>>>(gbuf, w2, 2048, 768, 3072,
                                      SKP, 6, 4, 2, 192, 768);
    comb4<2><<<768, 256, 0, stream>>>(SKP, out, mod + 8 * 768, nullptr, out);
}

// Round 18
// 216.201 us; speedup vs baseline: 1.0548x; 1.0548x over previous
//
#include <hip/hip_runtime.h>

typedef unsigned short u16;
typedef unsigned int u32;
typedef __attribute__((ext_vector_type(8))) short s16x8;
typedef __attribute__((ext_vector_type(4))) float f32x4;
typedef __attribute__((ext_vector_type(4))) int i32x4;

#define PS 1572864  // 2048*768 partial stride (elems)

// weight-wall element offsets
#define OFF_SAQKV  0
#define OFF_SAPROJ 1769472
#define OFF_CAQ    2359296
#define OFF_CAPROJ 2949120
#define OFF_W1     3538944
#define OFF_W2     5898240
#define OFF_W3     8257536

// ---------- bf16 helpers (bit-level, RNE) ----------
static __device__ __forceinline__ float bf2f(u16 u) {
    return __uint_as_float(((u32)u) << 16);
}
static __device__ __forceinline__ u16 f2bf(float f) {
    u32 x = __float_as_uint(f);
    return (u16)((x + 0x7fffu + ((x >> 16) & 1u)) >> 16);
}
static __device__ __forceinline__ i32x4 pack8(float4 a, float4 b) {
    u32 p0 = (u32)f2bf(a.x) | ((u32)f2bf(a.y) << 16);
    u32 p1 = (u32)f2bf(a.z) | ((u32)f2bf(a.w) << 16);
    u32 p2 = (u32)f2bf(b.x) | ((u32)f2bf(b.y) << 16);
    u32 p3 = (u32)f2bf(b.z) | ((u32)f2bf(b.w) << 16);
    return (i32x4){(int)p0, (int)p1, (int)p2, (int)p3};
}
static __device__ __forceinline__ float wave_sum(float v) {
#pragma unroll
    for (int off = 32; off > 0; off >>= 1) v += __shfl_xor(v, off);
    return v;
}
// async global->LDS, 16B per lane; dest is wave-uniform base (+lane*16 by HW)
static __device__ __forceinline__ void gload16(const void* g, void* l) {
    __builtin_amdgcn_global_load_lds((const __attribute__((address_space(1))) void*)g,
                                     (__attribute__((address_space(3))) void*)l, 16, 0, 0);
}

// ---------- fused: all-weights fp32->bf16 + adaLN GEMM + CA K/V prep ----------
__global__ __launch_bounds__(256) void cvt_ada(const float* __restrict__ s0,
                                               const float* __restrict__ s1,
                                               const float* __restrict__ s2,
                                               const float* __restrict__ s3,
                                               const float* __restrict__ s4,
                                               const float* __restrict__ s5,
                                               const float* __restrict__ s6,
                                               u16* __restrict__ wall,
                                               const float* __restrict__ c,
                                               const float* __restrict__ adaw,
                                               const float* __restrict__ adab,
                                               float* __restrict__ mod,
                                               const float* __restrict__ cond,
                                               const float* __restrict__ cnw,
                                               const float* __restrict__ cakw,
                                               const float* __restrict__ cavw,
                                               const float* __restrict__ caknw,
                                               float* __restrict__ kca,
                                               float* __restrict__ vca) {
    const int bid = blockIdx.x;
    const int tid = threadIdx.x;
    if (bid < 5184) {
        int u = bid * 256 + tid;
        const float* src;
        int rel;
        if (u < 221184)       { src = s0; rel = u; }
        else if (u < 294912)  { src = s1; rel = u - 221184; }
        else if (u < 368640)  { src = s2; rel = u - 294912; }
        else if (u < 442368)  { src = s3; rel = u - 368640; }
        else if (u < 737280)  { src = s4; rel = u - 442368; }
        else if (u < 1032192) { src = s5; rel = u - 737280; }
        else                  { src = s6; rel = u - 1032192; }
        float4 a = *(const float4*)(src + (size_t)rel * 8);
        float4 b = *(const float4*)(src + (size_t)rel * 8 + 4);
        *(i32x4*)(wall + (size_t)u * 8) = pack8(a, b);
    } else if (bid < 6912) {
        int wid = (bid - 5184) * 4 + (tid >> 6);
        int lane = tid & 63;
        float sum = 0.f;
#pragma unroll
        for (int i = 0; i < 12; ++i) {
            float cv = c[i * 64 + lane];
            cv = cv / (1.f + __expf(-cv));
            sum += cv * adaw[(size_t)wid * 768 + i * 64 + lane];
        }
        sum = wave_sum(sum);
        if (lane == 0) mod[wid] = sum + adab[wid];
    } else {
        int b = bid - 6912;
        int which = b / 192;
        int rem = b % 192;
        int rrow = rem / 12, h = rem % 12;
        int w = tid >> 6, lane = tid & 63;
        __shared__ float kvsh[64];
        float cv[12];
        float ss = 0.f;
#pragma unroll
        for (int i = 0; i < 12; ++i) {
            cv[i] = cond[(size_t)rrow * 768 + i * 64 + lane];
            ss += cv[i] * cv[i];
        }
        ss = wave_sum(ss);
        float rn = rsqrtf(ss * (1.f / 768.f) + 1e-6f);
#pragma unroll
        for (int i = 0; i < 12; ++i) cv[i] = cv[i] * rn * cnw[i * 64 + lane];
        const float* Wm = which ? cavw : cakw;
#pragma unroll
        for (int j = 0; j < 16; ++j) {
            int ocol = h * 64 + w * 16 + j;
            float d = 0.f;
#pragma unroll
            for (int i = 0; i < 12; ++i)
                d += cv[i] * Wm[(size_t)ocol * 768 + i * 64 + lane];
            d = wave_sum(d);
            if (lane == 0) kvsh[w * 16 + j] = d;
        }
        __syncthreads();
        if (tid < 64) {
            float v = kvsh[lane];
            if (which == 0) {
                float sk = wave_sum(v * v);
                v = v * rsqrtf(sk * (1.f / 64.f) + 1e-6f) * caknw[lane];
                kca[(size_t)rrow * 768 + h * 64 + lane] = v;
            } else {
                vca[(size_t)rrow * 768 + h * 64 + lane] = v;
            }
        }
    }
}

// ---------- fused RMSNorm + modulate, writes bf16 ----------
__global__ __launch_bounds__(256) void rms_mod(const float* __restrict__ x,
                                               const float* __restrict__ w,
                                               const float* __restrict__ mod, int chunk,
                                               u16* __restrict__ out) {
    const int row = blockIdx.x;
    const int tid = threadIdx.x;
    const float* xr = x + (size_t)row * 768;
    float v0 = xr[tid], v1 = xr[256 + tid], v2 = xr[512 + tid];
    float ss = wave_sum(v0 * v0 + v1 * v1 + v2 * v2);
    __shared__ float red[4];
    if ((tid & 63) == 0) red[tid >> 6] = ss;
    __syncthreads();
    float rn = rsqrtf((red[0] + red[1] + red[2] + red[3]) * (1.f / 768.f) + 1e-6f);
    const float* sh = mod + chunk * 768;
    const float* sc = sh + 768;
    u16* orow = out + (size_t)row * 768;
    orow[tid]       = f2bf(v0 * rn * w[tid]       * (1.f + sc[tid])       + sh[tid]);
    orow[256 + tid] = f2bf(v1 * rn * w[256 + tid] * (1.f + sc[256 + tid]) + sh[256 + tid]);
    orow[512 + tid] = f2bf(v2 * rn * w[512 + tid] * (1.f + sc[512 + tid]) + sh[512 + tid]);
}

// ---------- qkv GEMM with fused QK RMSNorm+RoPE and V-transpose epilogue ----------
__global__ __launch_bounds__(256) void gemm_qkv(const u16* __restrict__ A,
                                                const u16* __restrict__ Wb,
                                                u16* __restrict__ qkvb,
                                                u16* __restrict__ vT,
                                                const float* __restrict__ qnw,
                                                const float* __restrict__ knw,
                                                const float* __restrict__ cosT,
                                                const float* __restrict__ sinT,
                                                int C, int R, int nxc) {
    constexpr int K = 768, N = 2304;
    __shared__ __align__(16) char smem[33792];
    u16 (*As)[128 * 32] = (u16(*)[128 * 32])smem;
    u16 (*Bs)[64 * 32] = (u16(*)[64 * 32])(smem + 16384);
    const int tid = threadIdx.x;
    const int lane = tid & 63;
    const int w = tid >> 6;
    const int wr = w >> 1, wc = w & 1;
    const int sub = blockIdx.x;
    const int xcd = sub & 7, idx = sub >> 3;
    const int cx = xcd % nxc, cy = xcd / nxc;
    const int col0 = (cx * C + idx % C) << 6;
    const int row0 = (cy * R + idx / C) << 7;

    const int r0u = tid >> 2, s0u = (tid & 3) ^ (r0u & 3);
    const int r1u = (tid + 256) >> 2, s1u = (tid & 3) ^ (r1u & 3);
    const u16* a0 = A + (size_t)(row0 + r0u) * K + s0u * 8;
    const u16* a1 = A + (size_t)(row0 + r1u) * K + s1u * 8;
    const u16* b0 = Wb + (size_t)(col0 + r0u) * K + s0u * 8;

    f32x4 acc[4][2];
#pragma unroll
    for (int m = 0; m < 4; ++m)
#pragma unroll
        for (int n = 0; n < 2; ++n) acc[m][n] = (f32x4){0.f, 0.f, 0.f, 0.f};

    const int nt = K >> 5;
    int cur = 0;
#define QKV_STAGE(buf, k0)                                  \
    {                                                       \
        char* ad = (char*)As[buf] + w * 1024;               \
        char* bd = (char*)Bs[buf] + w * 1024;               \
        gload16(a0 + (k0), ad);                             \
        gload16(a1 + (k0), ad + 4096);                      \
        gload16(b0 + (k0), bd);                             \
    }
    QKV_STAGE(0, 0)
    for (int t = 0; t < nt; ++t) {
        __syncthreads();
        if (t + 1 < nt) QKV_STAGE(cur ^ 1, (t + 1) << 5)
        s16x8 af[4], bfv[2];
#pragma unroll
        for (int m = 0; m < 4; ++m) {
            int ra = wr * 64 + m * 16 + (lane & 15);
            int u = (lane >> 4) ^ (ra & 3);
            af[m] = *(const s16x8*)((const char*)As[cur] + ra * 64 + u * 16);
        }
#pragma unroll
        for (int n = 0; n < 2; ++n) {
            int cb = wc * 32 + n * 16 + (lane & 15);
            int u = (lane >> 4) ^ (cb & 3);
            bfv[n] = *(const s16x8*)((const char*)Bs[cur] + cb * 64 + u * 16);
        }
#pragma unroll
        for (int m = 0; m < 4; ++m)
#pragma unroll
            for (int n = 0; n < 2; ++n)
                acc[m][n] = __builtin_amdgcn_mfma_f32_16x16x32_bf16(af[m], bfv[n], acc[m][n], 0, 0, 0);
        cur ^= 1;
    }
#undef QKV_STAGE
    __syncthreads();

    const int region = col0 / 768;           // 0=q 1=k 2=v
    const int h = (col0 % 768) >> 6;
    if (region < 2) {
        float (*T)[66] = (float(*)[66])smem;
#pragma unroll
        for (int m = 0; m < 4; ++m)
#pragma unroll
            for (int n = 0; n < 2; ++n)
#pragma unroll
                for (int i = 0; i < 4; ++i)
                    T[wr * 64 + m * 16 + (lane >> 4) * 4 + i]
                     [wc * 32 + n * 16 + (lane & 15)] = acc[m][n][i];
        __syncthreads();
        const float* wv = region ? knw : qnw;
        const int rl = tid >> 1, half = (tid & 1) * 32;
        float ss = 0.f;
#pragma unroll
        for (int d = 0; d < 32; ++d) {
            float v = T[rl][half + d];
            ss += v * v;
        }
        ss += __shfl_xor(ss, 1);
        float rn = rsqrtf(ss * (1.f / 64.f) + 1e-6f);
        const int ng = row0 + rl;
        u16* orow = qkvb + (size_t)ng * N + col0;
        const float* cr = cosT + ng * 64;
        const float* sr = sinT + ng * 64;
#pragma unroll
        for (int d = 0; d < 32; ++d) {
            int dd = half + d;
            float vn = T[rl][dd] * rn * wv[dd];
            float pt = T[rl][dd ^ 32] * rn * wv[dd ^ 32];
            float rot = (dd < 32) ? -pt : pt;
            orow[dd] = f2bf(vn * cr[dd] + rot * sr[dd]);
        }
    } else {
        u16 (*Tb)[66] = (u16(*)[66])smem;
#pragma unroll
        for (int m = 0; m < 4; ++m)
#pragma unroll
            for (int n = 0; n < 2; ++n)
#pragma unroll
                for (int i = 0; i < 4; ++i) {
                    int rl = wr * 64 + m * 16 + (lane >> 4) * 4 + i;
                    int dd = wc * 32 + n * 16 + (lane & 15);
                    u16 b = f2bf(acc[m][n][i]);
                    qkvb[(size_t)(row0 + rl) * N + col0 + dd] = b;
                    Tb[rl][dd] = b;
                }
        __syncthreads();
        u16* dst = vT + (size_t)h * 131072 + (size_t)lane * 2048 + row0 + w * 32;
#pragma unroll
        for (int g = 0; g < 4; ++g) {
            s16x8 o;
#pragma unroll
            for (int e = 0; e < 8; ++e) o[e] = (short)Tb[w * 32 + g * 8 + e][lane];
            *(s16x8*)(dst + g * 8) = o;
        }
    }
}

// ---------- split-K=4 GEMM: BN=64, z = bid/nsub; writes bf16 partial z ----------
__global__ __launch_bounds__(256) void gemm_sk4(const u16* __restrict__ A,
                                                const u16* __restrict__ Wb,
                                                int M, int N, int K,
                                                u16* __restrict__ pz,
                                                int C, int R, int nxc,
                                                int nsub, int kslice) {
    __shared__ __align__(16) u16 As[2][128 * 32];
    __shared__ __align__(16) u16 Bs[2][64 * 32];
    const int tid = threadIdx.x;
    const int lane = tid & 63;
    const int w = tid >> 6;
    const int wr = w >> 1, wc = w & 1;
    const int sub = blockIdx.x % nsub;
    const int z = blockIdx.x / nsub;
    const int xcd = sub & 7, idx = sub >> 3;
    const int cx = xcd % nxc, cy = xcd / nxc;
    const int col0 = (cx * C + idx % C) << 6;
    const int row0 = (cy * R + idx / C) << 7;
    const int kbase = z * kslice;

    const int r0u = tid >> 2, s0u = (tid & 3) ^ (r0u & 3);
    const int r1u = (tid + 256) >> 2, s1u = (tid & 3) ^ (r1u & 3);
    const u16* a0 = A + (size_t)(row0 + r0u) * K + kbase + s0u * 8;
    const u16* a1 = A + (size_t)(row0 + r1u) * K + kbase + s1u * 8;
    const u16* b0 = Wb + (size_t)(col0 + r0u) * K + kbase + s0u * 8;

    f32x4 acc[4][2];
#pragma unroll
    for (int m = 0; m < 4; ++m)
#pragma unroll
        for (int n = 0; n < 2; ++n) acc[m][n] = (f32x4){0.f, 0.f, 0.f, 0.f};

    const int nt = kslice >> 5;
    int cur = 0;
#define SK_STAGE(buf, k0)                                   \
    {                                                       \
        char* ad = (char*)As[buf] + w * 1024;               \
        char* bd = (char*)Bs[buf] + w * 1024;               \
        gload16(a0 + (k0), ad);                             \
        gload16(a1 + (k0), ad + 4096);                      \
        gload16(b0 + (k0), bd);                             \
    }
    SK_STAGE(0, 0)
    for (int t = 0; t < nt; ++t) {
        __syncthreads();
        if (t + 1 < nt) SK_STAGE(cur ^ 1, (t + 1) << 5)
        s16x8 af[4], bfv[2];
#pragma unroll
        for (int m = 0; m < 4; ++m) {
            int ra = wr * 64 + m * 16 + (lane & 15);
            int u = (lane >> 4) ^ (ra & 3);
            af[m] = *(const s16x8*)((const char*)As[cur] + ra * 64 + u * 16);
        }
#pragma unroll
        for (int n = 0; n < 2; ++n) {
            int cb = wc * 32 + n * 16 + (lane & 15);
            int u = (lane >> 4) ^ (cb & 3);
            bfv[n] = *(const s16x8*)((const char*)Bs[cur] + cb * 64 + u * 16);
        }
#pragma unroll
        for (int m = 0; m < 4; ++m)
#pragma unroll
            for (int n = 0; n < 2; ++n)
                acc[m][n] = __builtin_amdgcn_mfma_f32_16x16x32_bf16(af[m], bfv[n], acc[m][n], 0, 0, 0);
        cur ^= 1;
    }
#undef SK_STAGE
    u16* po = pz + (size_t)z * PS;
#pragma unroll
    for (int m = 0; m < 4; ++m)
#pragma unroll
        for (int n = 0; n < 2; ++n)
#pragma unroll
            for (int i = 0; i < 4; ++i) {
                int r = row0 + wr * 64 + m * 16 + (lane >> 4) * 4 + i;
                int cc = col0 + wc * 32 + n * 16 + (lane & 15);
                po[(size_t)r * N + cc] = f2bf(acc[m][n][i]);
            }
}

// ---------- combine 4 split-K partials (elementwise) ----------
template <int MODE>
__global__ __launch_bounds__(256) void comb4(const u16* __restrict__ pz,
                                             const float* __restrict__ resid,
                                             const float* __restrict__ gate,
                                             const float* __restrict__ bias,
                                             float* __restrict__ outf) {
    int base = (blockIdx.x * 256 + threadIdx.x) * 8;
    int col = base % 768;
    s16x8 p0 = *(const s16x8*)(pz + base);
    s16x8 p1 = *(const s16x8*)(pz + PS + base);
    s16x8 p2 = *(const s16x8*)(pz + 2 * PS + base);
    s16x8 p3 = *(const s16x8*)(pz + 3 * PS + base);
    float o[8];
#pragma unroll
    for (int e = 0; e < 8; ++e) {
        float s = (bf2f((u16)p0[e]) + bf2f((u16)p1[e])) +
                  (bf2f((u16)p2[e]) + bf2f((u16)p3[e]));
        if constexpr (MODE == 0) {
            o[e] = s;
        } else {
            float bb = bias ? bias[col + e] : 0.f;
            o[e] = resid[base + e] + gate[col + e] * (s + bb);
        }
    }
    *(float4*)(outf + base) = (float4){o[0], o[1], o[2], o[3]};
    *(float4*)(outf + base + 4) = (float4){o[4], o[5], o[6], o[7]};
}

// ---------- fused: combine 4 partials + residual + RMSNorm + modulate ----------
__global__ __launch_bounds__(256) void comb_rms(const u16* __restrict__ pz,
                                                const float* __restrict__ resid,
                                                const float* __restrict__ gate,
                                                const float* __restrict__ bias,
                                                const float* __restrict__ mod, int chunk,
                                                const float* __restrict__ w,
                                                float* __restrict__ outf,
                                                u16* __restrict__ outb) {
    const int row = blockIdx.x;
    const int tid = threadIdx.x;
    float val[3];
    float ss = 0.f;
#pragma unroll
    for (int j = 0; j < 3; ++j) {
        int col = tid + j * 256;
        size_t ix = (size_t)row * 768 + col;
        float s = (bf2f(pz[ix]) + bf2f(pz[PS + ix])) +
                  (bf2f(pz[2 * PS + ix]) + bf2f(pz[3 * PS + ix]));
        float bb = bias ? bias[col] : 0.f;
        float v = resid[ix] + gate[col] * (s + bb);
        val[j] = v;
        ss += v * v;
        outf[ix] = v;
    }
    ss = wave_sum(ss);
    __shared__ float red[4];
    if ((tid & 63) == 0) red[tid >> 6] = ss;
    __syncthreads();
    float rn = rsqrtf((red[0] + red[1] + red[2] + red[3]) * (1.f / 768.f) + 1e-6f);
    const float* sh = mod + chunk * 768;
    const float* sc = sh + 768;
#pragma unroll
    for (int j = 0; j < 3; ++j) {
        int col = tid + j * 256;
        size_t ix = (size_t)row * 768 + col;
        outb[ix] = f2bf(val[j] * rn * w[col] * (1.f + sc[col]) + sh[col]);
    }
}

// ---------- fused CA: combine 4 q partials + RMS + RoPE + attention ----------
__global__ __launch_bounds__(256) void ca_fused(const u16* __restrict__ pz,
                                                const float* __restrict__ qnw,
                                                const float* __restrict__ cosT,
                                                const float* __restrict__ sinT,
                                                const float* __restrict__ kca,
                                                const float* __restrict__ vca,
                                                u16* __restrict__ obuf) {
    int wid = blockIdx.x * 4 + (threadIdx.x >> 6);
    int lane = threadIdx.x & 63;
    int n = wid / 12, h = wid % 12;
    size_t ix = (size_t)n * 768 + h * 64 + lane;
    float v = (bf2f(pz[ix]) + bf2f(pz[PS + ix])) +
              (bf2f(pz[2 * PS + ix]) + bf2f(pz[3 * PS + ix]));
    float ss = wave_sum(v * v);
    float vn = v * rsqrtf(ss * (1.f / 64.f) + 1e-6f) * qnw[lane];
    float part = __shfl_xor(vn, 32);
    float rot = (lane < 32) ? -part : part;
    float qd = (vn * cosT[n * 64 + lane] + rot * sinT[n * 64 + lane]) * 0.125f;
    float s[16];
#pragma unroll
    for (int j = 0; j < 16; ++j)
        s[j] = wave_sum(qd * kca[(size_t)j * 768 + h * 64 + lane]);
    float mm = s[0];
#pragma unroll
    for (int j = 1; j < 16; ++j) mm = fmaxf(mm, s[j]);
    float l = 0.f;
#pragma unroll
    for (int j = 0; j < 16; ++j) { s[j] = __expf(s[j] - mm); l += s[j]; }
    float od = 0.f;
#pragma unroll
    for (int j = 0; j < 16; ++j) od += s[j] * vca[(size_t)j * 768 + h * 64 + lane];
    obuf[ix] = f2bf(od / l);
}

// ---------- fused MLP-up: gbuf = bf16( silu(A@W1^T) * (A@W3^T) ), BN=64 ----------
__global__ __launch_bounds__(256) void gemm_w13(const u16* __restrict__ A,
                                                const u16* __restrict__ W1,
                                                const u16* __restrict__ W3,
                                                int M, int N, int K,
                                                u16* __restrict__ outb,
                                                int C, int R, int nxc) {
    __shared__ __align__(16) u16 As[2][128 * 32];
    __shared__ __align__(16) u16 B1s[2][64 * 32];
    __shared__ __align__(16) u16 B3s[2][64 * 32];
    const int tid = threadIdx.x;
    const int lane = tid & 63;
    const int w = tid >> 6;
    const int wr = w >> 1, wc = w & 1;
    const int sub = blockIdx.x;
    const int xcd = sub & 7, idx = sub >> 3;
    const int cx = xcd % nxc, cy = xcd / nxc;
    const int col0 = (cx * C + idx % C) << 6;
    const int row0 = (cy * R + idx / C) << 7;

    const int r0u = tid >> 2, s0u = (tid & 3) ^ (r0u & 3);
    const int r1u = (tid + 256) >> 2, s1u = (tid & 3) ^ (r1u & 3);
    const u16* a0 = A + (size_t)(row0 + r0u) * K + s0u * 8;
    const u16* a1 = A + (size_t)(row0 + r1u) * K + s1u * 8;
    const u16* b1p = W1 + (size_t)(col0 + r0u) * K + s0u * 8;
    const u16* b3p = W3 + (size_t)(col0 + r0u) * K + s0u * 8;

    f32x4 acc1[4][2], acc3[4][2];
#pragma unroll
    for (int m = 0; m < 4; ++m)
#pragma unroll
        for (int n = 0; n < 2; ++n) {
            acc1[m][n] = (f32x4){0.f, 0.f, 0.f, 0.f};
            acc3[m][n] = (f32x4){0.f, 0.f, 0.f, 0.f};
        }

    const int nt = K >> 5;
    int cur = 0;
#define W13_STAGE(buf, k0)                                  \
    {                                                       \
        char* ad = (char*)As[buf] + w * 1024;               \
        char* bd1 = (char*)B1s[buf] + w * 1024;             \
        char* bd3 = (char*)B3s[buf] + w * 1024;             \
        gload16(a0 + (k0), ad);                             \
        gload16(a1 + (k0), ad + 4096);                      \
        gload16(b1p + (k0), bd1);                           \
        gload16(b3p + (k0), bd3);                           \
    }
    W13_STAGE(0, 0)
    for (int t = 0; t < nt; ++t) {
        __syncthreads();
        if (t + 1 < nt) W13_STAGE(cur ^ 1, (t + 1) << 5)
        s16x8 af[4], b1v[2], b3v[2];
#pragma unroll
        for (int m = 0; m < 4; ++m) {
            int ra = wr * 64 + m * 16 + (lane & 15);
            int u = (lane >> 4) ^ (ra & 3);
            af[m] = *(const s16x8*)((const char*)As[cur] + ra * 64 + u * 16);
        }
#pragma unroll
        for (int n = 0; n < 2; ++n) {
            int cb = wc * 32 + n * 16 + (lane & 15);
            int u = (lane >> 4) ^ (cb & 3);
            b1v[n] = *(const s16x8*)((const char*)B1s[cur] + cb * 64 + u * 16);
            b3v[n] = *(const s16x8*)((const char*)B3s[cur] + cb * 64 + u * 16);
        }
#pragma unroll
        for (int m = 0; m < 4; ++m)
#pragma unroll
            for (int n = 0; n < 2; ++n) {
                acc1[m][n] = __builtin_amdgcn_mfma_f32_16x16x32_bf16(af[m], b1v[n], acc1[m][n], 0, 0, 0);
                acc3[m][n] = __builtin_amdgcn_mfma_f32_16x16x32_bf16(af[m], b3v[n], acc3[m][n], 0, 0, 0);
            }
        cur ^= 1;
    }
#undef W13_STAGE
#pragma unroll
    for (int m = 0; m < 4; ++m)
#pragma unroll
        for (int n = 0; n < 2; ++n)
#pragma unroll
            for (int i = 0; i < 4; ++i) {
                int r = row0 + wr * 64 + m * 16 + (lane >> 4) * 4 + i;
                int cc = col0 + wc * 32 + n * 16 + (lane & 15);
                float v1 = acc1[m][n][i];
                float g = v1 / (1.f + __expf(-v1));
                outb[(size_t)r * N + cc] = f2bf(g * acc3[m][n][i]);
            }
}

// ---------- SA flash attention, MFMA bf16, FIXED-MAX softmax + 4-way key split ----------
__global__ __launch_bounds__(256) void sa_attn_mfma(const u16* __restrict__ qkv,
                                                    const u16* __restrict__ vT,
                                                    u16* __restrict__ at,
                                                    float* __restrict__ pl) {
    const int h = blockIdx.y;
    const int r0 = blockIdx.x * 64;
    const int z = blockIdx.z;
    const int tid = threadIdx.x;
    const int lane = tid & 63;
    const int w = tid >> 6;
    __shared__ __align__(16) u16 Ks[2][64 * 64];
    __shared__ __align__(16) u16 Vs[2][64 * 64];
    __shared__ __align__(16) u16 Ps[4][16 * 64];

    s16x8 qf[2];
    {
        const u16* qrow = qkv + (size_t)(r0 + w * 16 + (lane & 15)) * 2304 + h * 64 + ((lane >> 4) * 8);
        qf[0] = *(const s16x8*)qrow;
        qf[1] = *(const s16x8*)(qrow + 32);
    }
    f32x4 oacc[4];
#pragma unroll
    for (int n = 0; n < 4; ++n) oacc[n] = (f32x4){0.f, 0.f, 0.f, 0.f};
    float lp[4] = {0.f, 0.f, 0.f, 0.f};

    const u16* ksrc[2];
    const u16* vsrc[2];
#pragma unroll
    for (int j = 0; j < 2; ++j) {
        int u = (w * 2 + j) * 64 + lane;
        int row = u >> 3, seg = (u & 7) ^ (row & 7);
        ksrc[j] = qkv + (size_t)(z * 512 + row) * 2304 + 768 + h * 64 + seg * 8;
        vsrc[j] = vT + (size_t)h * 131072 + (size_t)row * 2048 + z * 512 + seg * 8;
    }

#define SA_STAGE(buf, t_)                                          \
    {                                                              \
        char* kd = (char*)Ks[buf] + w * 2048;                      \
        char* vd = (char*)Vs[buf] + w * 2048;                      \
        gload16(ksrc[0] + (size_t)(t_) * 147456, kd);              \
        gload16(ksrc[1] + (size_t)(t_) * 147456, kd + 1024);       \
        gload16(vsrc[0] + (t_) * 64, vd);                          \
        gload16(vsrc[1] + (t_) * 64, vd + 1024);                   \
    }

    SA_STAGE(0, 0)
    int cur = 0;
    for (int t = 0; t < 8; ++t) {
        __syncthreads();
        if (t + 1 < 8) SA_STAGE(cur ^ 1, t + 1)

        f32x4 sacc[4];
#pragma unroll
        for (int n = 0; n < 4; ++n) sacc[n] = (f32x4){0.f, 0.f, 0.f, 0.f};
#pragma unroll
        for (int kk = 0; kk < 2; ++kk) {
#pragma unroll
            for (int n = 0; n < 4; ++n) {
                int key = n * 16 + (lane & 15);
                int d = kk * 32 + (lane >> 4) * 8;
                int boff = key * 128 + ((d * 2) ^ ((key & 7) << 4));
                s16x8 kf = *(const s16x8*)((const char*)Ks[cur] + boff);
                sacc[n] = __builtin_amdgcn_mfma_f32_16x16x32_bf16(qf[kk], kf, sacc[n], 0, 0, 0);
            }
        }
        // fixed-max softmax: p = exp(s*0.125 - 8); |s*0.125| <= 8 by Cauchy-Schwarz
#pragma unroll
        for (int n = 0; n < 4; ++n) {
#pragma unroll
            for (int i = 0; i < 4; ++i) {
                float p = __expf(fmaf(sacc[n][i], 0.125f, -8.0f));
                lp[i] += p;
                int row = (lane >> 4) * 4 + i;
                int key = n * 16 + (lane & 15);
                int boff = row * 128 + ((key * 2) ^ ((row & 7) << 4));
                *(u16*)((char*)Ps[w] + boff) = f2bf(p);
            }
        }
#pragma unroll
        for (int kk = 0; kk < 2; ++kk) {
            int koff = kk * 32 + (lane >> 4) * 8;
            int prow = lane & 15;
            int pboff = prow * 128 + ((koff * 2) ^ ((prow & 7) << 4));
            s16x8 pf = *(const s16x8*)((const char*)Ps[w] + pboff);
#pragma unroll
            for (int n = 0; n < 4; ++n) {
                int d = n * 16 + (lane & 15);
                int vboff = d * 128 + ((koff * 2) ^ ((d & 7) << 4));
                s16x8 vf = *(const s16x8*)((const char*)Vs[cur] + vboff);
                oacc[n] = __builtin_amdgcn_mfma_f32_16x16x32_bf16(pf, vf, oacc[n], 0, 0, 0);
            }
        }
        cur ^= 1;
    }
#undef SA_STAGE
#pragma unroll
    for (int off = 1; off < 16; off <<= 1) {
#pragma unroll
        for (int i = 0; i < 4; ++i) lp[i] += __shfl_xor(lp[i], off);
    }
    u16* po = at + (size_t)z * PS;
#pragma unroll
    for (int n = 0; n < 4; ++n) {
#pragma unroll
        for (int i = 0; i < 4; ++i) {
            int r = r0 + w * 16 + (lane >> 4) * 4 + i;
            int d = n * 16 + (lane & 15);
            po[(size_t)r * 768 + h * 64 + d] = f2bf(oacc[n][i]);
        }
    }
    if ((lane & 15) == 0) {
#pragma unroll
        for (int i = 0; i < 4; ++i) {
            int r = r0 + w * 16 + (lane >> 4) * 4 + i;
            pl[z * 24576 + h * 2048 + r] = lp[i];
        }
    }
}

// ---------- combine 4 key-split partials: O = (sum O_z)/(sum l_z) ----------
__global__ __launch_bounds__(256) void sa_combine4(const u16* __restrict__ at,
                                                   const float* __restrict__ pl,
                                                   u16* __restrict__ obuf) {
    int idx = blockIdx.x * 256 + threadIdx.x;
    int base = idx * 8;
    int row = base / 768;
    int col = base % 768;
    int h = col >> 6;
    float l = (pl[h * 2048 + row] + pl[24576 + h * 2048 + row]) +
              (pl[49152 + h * 2048 + row] + pl[73728 + h * 2048 + row]);
    float inv = 1.f / l;
    s16x8 a = *(const s16x8*)(at + base);
    s16x8 b = *(const s16x8*)(at + PS + base);
    s16x8 cc = *(const s16x8*)(at + 2 * PS + base);
    s16x8 d = *(const s16x8*)(at + 3 * PS + base);
    s16x8 o;
#pragma unroll
    for (int e = 0; e < 8; ++e) {
        float s = (bf2f((u16)a[e]) + bf2f((u16)b[e])) +
                  (bf2f((u16)cc[e]) + bf2f((u16)d[e]));
        o[e] = (short)f2bf(s * inv);
    }
    *(s16x8*)(obuf + base) = o;
}

// =======================================================================
extern "C" void kernel_launch(void* const* d_in, const int* in_sizes, int n_in,
                              void* d_out, int out_size, void* d_ws, size_t ws_size,
                              hipStream_t stream) {
    const float* x     = (const float*)d_in[0];
    const float* c     = (const float*)d_in[1];
    const float* cond  = (const float*)d_in[2];
    const float* cosT  = (const float*)d_in[3];
    const float* sinT  = (const float*)d_in[4];
    const float* n1w   = (const float*)d_in[5];
    const float* n2w   = (const float*)d_in[6];
    const float* n3w   = (const float*)d_in[7];
    const float* cnw   = (const float*)d_in[8];
    const float* saqkvw  = (const float*)d_in[9];
    const float* saprojw = (const float*)d_in[10];
    const float* saprojb = (const float*)d_in[11];
    const float* saqnw   = (const float*)d_in[12];
    const float* saknw   = (const float*)d_in[13];
    const float* caqw    = (const float*)d_in[14];
    const float* cakw    = (const float*)d_in[15];
    const float* cavw    = (const float*)d_in[16];
    const float* caprojw = (const float*)d_in[17];
    const float* caprojb = (const float*)d_in[18];
    const float* caqnw   = (const float*)d_in[19];
    const float* caknw   = (const float*)d_in[20];
    const float* w1      = (const float*)d_in[21];
    const float* w2      = (const float*)d_in[22];
    const float* w3      = (const float*)d_in[23];
    const float* adaw    = (const float*)d_in[24];
    const float* adab    = (const float*)d_in[25];
    float* out = (float*)d_out;
    char* ws = (char*)d_ws;

    float* mod  = (float*)ws;                      // 27,648
    u16* hbuf   = (u16*)(ws + 32768);              // 3,145,728
    u16* obuf   = (u16*)(ws + 3178496);            // 3,145,728
    char* R1    = ws + 6324224;                    // shared region
    u16* qkvb   = (u16*)R1;                        //   qkv bf16 [2048][2304]
    u16* vTb    = (u16*)(R1 + 9437184);            //   V^T bf16 [12][64][2048]
    u16* gbuf   = (u16*)R1;                        //   MLP gate bf16 [2048][3072]
    float* kca  = (float*)(ws + 18956288);
    float* vca  = (float*)(ws + 19005440);
    u16* WALL   = (u16*)(ws + 19054592);           // all weights bf16
    u16* AT     = (u16*)(ws + 40288256);           // attn partials [4][2048][768]
    float* PL4  = (float*)(ws + 52871168);         // attn l [4][12][2048]
    u16* SKP    = (u16*)(ws + 53264384);           // split-K partials [4][2048][768]

    // 1. weight conversion + adaLN + CA K/V prep, one kernel
    cvt_ada<<<7296, 256, 0, stream>>>(saqkvw, saprojw, caqw, caprojw, w1, w2, w3,
                                      WALL, c, adaw, adab, mod,
                                      cond, cnw, cakw, cavw, caknw, kca, vca);

    // ---- self-attention ----
    rms_mod<<<2048, 256, 0, stream>>>(x, n1w, mod, 0, hbuf);
    gemm_qkv<<<576, 256, 0, stream>>>(hbuf, WALL + OFF_SAQKV, qkvb, vTb,
                                      saqnw, saknw, cosT, sinT, 9, 8, 4);
    sa_attn_mfma<<<dim3(32, 12, 4), 256, 0, stream>>>(qkvb, vTb, AT, PL4);
    sa_combine4<<<768, 256, 0, stream>>>(AT, PL4, obuf);
    gemm_sk4<<<768, 256, 0, stream>>>(obuf, WALL + OFF_SAPROJ, 2048, 768, 768,
                                      SKP, 6, 4, 2, 192, 192);
    comb_rms<<<2048, 256, 0, stream>>>(SKP, x, mod + 2 * 768, saprojb,
                                       mod, 3, n2w, out, hbuf);

    // ---- cross-attention ----
    gemm_sk4<<<768, 256, 0, stream>>>(hbuf, WALL + OFF_CAQ, 2048, 768, 768,
                                      SKP, 6, 4, 2, 192, 192);
    ca_fused<<<6144, 256, 0, stream>>>(SKP, caqnw, cosT, sinT, kca, vca, obuf);
    gemm_sk4<<<768, 256, 0, stream>>>(obuf, WALL + OFF_CAPROJ, 2048, 768, 768,
                                      SKP, 6, 4, 2, 192, 192);
    comb_rms<<<2048, 256, 0, stream>>>(SKP, out, mod + 5 * 768, caprojb,
                                       mod, 6, n3w, out, hbuf);

    // ---- SwiGLU MLP ----
    gemm_w13<<<768, 256, 0, stream>>>(hbuf, WALL + OFF_W1, WALL + OFF_W3,
                                      2048, 3072, 768, gbuf, 12, 8, 4);
    gemm_sk4<<<768, 256, 0, stream>>>(gbuf, WALL + OFF_W2, 2048, 768, 3072,
                                      SKP, 6, 4, 2, 192, 768);
    comb4<2><<<768, 256, 0, stream>>>(SKP, out, mod + 8 * 768, nullptr, out);
}